// Round 7
// baseline (925.712 us; speedup 1.0000x reference)
//
#include <hip/hip_runtime.h>

#define B_    16
#define T_    8192
#define D_    512
#define K_    8192
#define S_    1024
#define N_    16384      // B_*S_
#define NBT   131072     // B_*T_

// d_out float offsets
#define LOSS_OFF 67108864
#define IDX_OFF  67108865
#define BND_OFF  67239937

typedef __bf16 bf16x8 __attribute__((ext_vector_type(8)));
typedef float  f32x4  __attribute__((ext_vector_type(4)));

__device__ __forceinline__ unsigned int fsort(float f){
  unsigned int u = __float_as_uint(f);
  return (u & 0x80000000u) ? ~u : (u | 0x80000000u);
}
__device__ __forceinline__ float funsort(unsigned int su){
  unsigned int u = (su & 0x80000000u) ? (su ^ 0x80000000u) : ~su;
  return __uint_as_float(u);
}
__device__ __forceinline__ unsigned short f2bf(float f){
  unsigned int u = __float_as_uint(f);
  return (unsigned short)((u + 0x7fffu + ((u >> 16) & 1u)) >> 16);
}

#define SETP1()    __builtin_amdgcn_s_setprio(1)
#define SETP0()    __builtin_amdgcn_s_setprio(0)

// |emb_k|^2 (one wave per codebook row) + bf16 copy of emb; block 0 inits cnt
__global__ void k_embnorm(const float4* __restrict__ emb4, float* __restrict__ enorm,
                          unsigned short* __restrict__ embh, int* __restrict__ cnt){
  if(blockIdx.x == 0 && threadIdx.x == 0) *cnt = 0;
  const int wid  = (blockIdx.x * blockDim.x + threadIdx.x) >> 6;   // 0..8191
  const int lane = threadIdx.x & 63;
  float4 a = emb4[wid * 128 + (lane << 1)];
  float4 b = emb4[wid * 128 + (lane << 1) + 1];
  float s = a.x*a.x + a.y*a.y + a.z*a.z + a.w*a.w
          + b.x*b.x + b.y*b.y + b.z*b.z + b.w*b.w;
  #pragma unroll
  for(int off = 32; off; off >>= 1) s += __shfl_xor(s, off);
  if(lane == 0) enorm[wid] = s;
  unsigned short* dst = embh + ((size_t)wid << 9) + (lane << 3);
  *(ushort4*)(dst)     = make_ushort4(f2bf(a.x), f2bf(a.y), f2bf(a.z), f2bf(a.w));
  *(ushort4*)(dst + 4) = make_ushort4(f2bf(b.x), f2bf(b.y), f2bf(b.z), f2bf(b.w));
}

// Fused: boundary (fp64 dot, parallel over 128 lanes) + mean-pool + bf16 convert.
// One block = 32 t-rows = 4 segments; reads x exactly once.
__launch_bounds__(256)
__global__ void k_prep(const float4* __restrict__ x4, const float4* __restrict__ wb4,
                       const float* __restrict__ bb, float4* __restrict__ pooled4,
                       unsigned short* __restrict__ pooledh, float* __restrict__ bnd,
                       int* __restrict__ cnt){
  __shared__ double ld[4][8][8];          // [seg_l][row_l][16-lane group]
  const int tid  = threadIdx.x;
  const int row0 = blockIdx.x << 5;       // first global t-row of this block
  const double bbv = (double)bb[0];
  #pragma unroll
  for(int it = 0; it < 2; it++){
    const int slot  = (it << 8) + tid;    // 0..511 = (seg_l:4) x (c4:128)
    const int seg_l = slot >> 7;
    const int c4    = slot & 127;
    const float4 w  = wb4[c4];
    const float4* src = x4 + ((size_t)(row0 + (seg_l << 3)) * 128 + c4);
    float4 acc = src[0];
    double p[8];
    p[0] = (double)acc.x*w.x + (double)acc.y*w.y + (double)acc.z*w.z + (double)acc.w*w.w;
    #pragma unroll
    for(int t = 1; t < 8; t++){
      const float4 v = src[(size_t)t * 128];
      acc.x += v.x; acc.y += v.y; acc.z += v.z; acc.w += v.w;
      p[t] = (double)v.x*w.x + (double)v.y*w.y + (double)v.z*w.z + (double)v.w*w.w;
    }
    acc.x *= 0.125f; acc.y *= 0.125f; acc.z *= 0.125f; acc.w *= 0.125f;
    const int u = ((blockIdx.x << 2) + seg_l) * 128 + c4;
    pooled4[u] = acc;
    *(ushort4*)(pooledh + ((size_t)u << 2)) =
        make_ushort4(f2bf(acc.x), f2bf(acc.y), f2bf(acc.z), f2bf(acc.w));
    #pragma unroll
    for(int t = 0; t < 8; t++){
      #pragma unroll
      for(int off = 1; off < 16; off <<= 1) p[t] += __shfl_xor(p[t], off);
    }
    if((c4 & 15) == 0){
      #pragma unroll
      for(int t = 0; t < 8; t++) ld[seg_l][t][c4 >> 4] = p[t];
    }
  }
  __syncthreads();
  if(tid < 32){
    const double* q = ld[tid >> 3][tid & 7];
    double s = bbv;
    #pragma unroll
    for(int h = 0; h < 8; h++) s += q[h];
    const bool f = s > 0.0;
    bnd[row0 + tid] = f ? 1.0f : 0.0f;
    const unsigned long long m = __ballot(f);
    if(tid == 0) atomicAdd(cnt, (int)__popcll(m));
  }
}

// bf16 MFMA distance GEMM, FLATMM style (AITER s02 pattern): NO LDS, NO
// BARRIERS. MFMA fragments load DIRECT from global into registers with
// per-lane addresses (4 q-lanes per row cover one contiguous 64B line; A slab
// 2MB + B panel 256KB are XCD-L2-resident via the slab swizzle). Ping-pong
// register sets (named a0/b0/a1/b1 -> static indexing), 2-step prefetch depth;
// compiler derives counted vmcnt(12) before each consume. 8 independent waves.
// Rationale: LDS-operand path caps MfmaUtil at ~27% (96KB LDS reads/step/CU =
// ~1150cy vs 310cy MFMA, barrier-serialized) -- measured 26-28.5% across 5
// schedule variants. Direct-from-L2 removes that wall entirely.
__launch_bounds__(512, 2)
__global__ void k_distx(const unsigned short* __restrict__ Ah,
                        const unsigned short* __restrict__ Bh,
                        const float* __restrict__ enorm,
                        unsigned long long* __restrict__ cand64){
  const int tid  = threadIdx.x;
  const int w    = tid >> 6, lane = tid & 63;
  const int wm   = w >> 2,  wn   = w & 3;        // 2x4 wave grid; wave = 128x64 out
  const int c    = lane & 15, q  = lane >> 4;

  const int bid   = blockIdx.x;
  const int xcd   = bid & 7;
  const int local = bid >> 3;                    // 0..255 within XCD
  const int row_t = (xcd << 3) + (local & 7);    // 0..63  (8-row-tile slab per XCD)
  const int col_t = local >> 3;                  // 0..31  (col-major sweep)
  const int rowbase = row_t << 8;
  const int colbase = col_t << 8;

  f32x4 acc[8][4];
  #pragma unroll
  for(int i = 0; i < 8; i++)
    #pragma unroll
    for(int j = 0; j < 4; j++) acc[i][j] = (f32x4){0.f, 0.f, 0.f, 0.f};

  // per-lane fragment base pointers: row (…+c), k-chunk q*8 elements.
  // A frag i: rows wm*128 + i*16 + c  (i stride = 16 rows = 8192 ushorts)
  // B frag j: rows colbase + wn*64 + j*16 + c
  const unsigned short* Ap = Ah + (size_t)(rowbase + wm*128 + c) * 512 + q*8;
  const unsigned short* Bp = Bh + (size_t)(colbase + wn*64 + c) * 512 + q*8;

  bf16x8 a0[8], b0[4], a1[8], b1[4];

  #define LDA(dst, kb) do{ _Pragma("unroll")                                   \
    for(int i = 0; i < 8; i++)                                                 \
      dst[i] = *(const bf16x8*)(Ap + (size_t)i*8192 + (kb)); }while(0)
  #define LDB(dst, kb) do{ _Pragma("unroll")                                   \
    for(int j = 0; j < 4; j++)                                                 \
      dst[j] = *(const bf16x8*)(Bp + (size_t)j*8192 + (kb)); }while(0)
  #define MM(af, bg) do{ SETP1(); _Pragma("unroll")                            \
    for(int i = 0; i < 8; i++) _Pragma("unroll")                               \
      for(int j = 0; j < 4; j++)                                               \
        acc[i][j] = __builtin_amdgcn_mfma_f32_16x16x32_bf16(                   \
            af[i], bg[j], acc[i][j], 0, 0, 0);                                 \
    SETP0(); }while(0)

  // prologue: preload steps 0,1 (2-deep register pipeline)
  LDA(a0, 0);  LDB(b0, 0);
  LDA(a1, 32); LDB(b1, 32);

  // steady: compute set, then refill it for step t+2 (latency hides under the
  // other set's 32-MFMA cluster + next compute; compiler emits vmcnt(12) waits)
  #pragma unroll 1
  for(int u = 0; u < 7; ++u){
    const int kb = u << 6;                        // = t*32, t = 2u
    MM(a0, b0);
    LDA(a0, kb + 64); LDB(b0, kb + 64);           // step 2u+2
    MM(a1, b1);
    LDA(a1, kb + 96); LDB(b1, kb + 96);           // step 2u+3
  }
  MM(a0, b0);                                     // step 14
  MM(a1, b1);                                     // step 15

  #undef LDA
  #undef LDB
  #undef MM

  // epilogue: dist = enorm - 2*dot; in-thread top-2 over 4 j-cols, 4-step
  // butterfly over 16 c-lanes -> top-2 per 64-col group; lane c==0 stores u64.
  float en[4];
  #pragma unroll
  for(int j = 0; j < 4; j++) en[j] = enorm[colbase + wn*64 + j*16 + c];

  #pragma unroll
  for(int i = 0; i < 8; i++){
    #pragma unroll
    for(int r = 0; r < 4; r++){
      unsigned int k1 = 0xffffffffu, k2 = 0xffffffffu;
      #pragma unroll
      for(int j = 0; j < 4; j++){
        const float d = fmaf(-2.0f, acc[i][j][r], en[j]);
        const unsigned int col = (unsigned int)(colbase + wn*64 + j*16 + c);
        const unsigned int key = (fsort(d) & 0xffffe000u) | col;
        if(key < k1){ k2 = k1; k1 = key; } else if(key < k2){ k2 = key; }
      }
      #pragma unroll
      for(int off = 1; off < 16; off <<= 1){
        const unsigned int o1 = __shfl_xor(k1, off);
        const unsigned int o2 = __shfl_xor(k2, off);
        if(o1 < k1){ k2 = min(k1, o2); k1 = o1; }
        else       { k2 = min(k2, o1); }
      }
      if(c == 0){
        const int row = rowbase + wm*128 + i*16 + (q << 2) + r;
        cand64[((size_t)row << 7) + (col_t << 2) + wn] =
            ((unsigned long long)k2 << 32) | k1;
      }
    }
  }
}

// fp64 rescore of candidates within margin of min -> exact argmin + per-row loss term
__launch_bounds__(256)
__global__ void k_fixup(const float* __restrict__ pooled, const float* __restrict__ emb,
                        const unsigned long long* __restrict__ cand64,
                        int* __restrict__ idxf, double* __restrict__ part){
  const int lane = threadIdx.x & 63, wv = threadIdx.x >> 6;
  const int row = (blockIdx.x << 2) + wv;
  const ulonglong2* cr = (const ulonglong2*)(cand64 + ((size_t)row << 7));
  const ulonglong2 v = cr[lane];
  unsigned int ks[4];
  ks[0] = (unsigned int)v.x; ks[1] = (unsigned int)(v.x >> 32);
  ks[2] = (unsigned int)v.y; ks[3] = (unsigned int)(v.y >> 32);
  unsigned int mn = min(min(ks[0], ks[1]), min(ks[2], ks[3]));
  #pragma unroll
  for(int off = 32; off; off >>= 1) mn = min(mn, (unsigned int)__shfl_xor(mn, off));
  const float thr = funsort(mn & 0xffffe000u) + 0.01f;   // covers bf16 + key-trunc error

  double bestd = 1e300; int besti = 0x7fffffff;
  const float4* p4 = (const float4*)(pooled + ((size_t)row << 9));
  const float4 pa = p4[lane << 1], pb = p4[(lane << 1) + 1];
  #pragma unroll
  for(int g = 0; g < 4; g++){
    const bool flag = funsort(ks[g] & 0xffffe000u) <= thr;
    unsigned long long mask = __ballot(flag);
    while(mask){
      const int l = __ffsll(mask) - 1;
      mask &= mask - 1;
      const int code = (int)(__shfl(ks[g], l) & 0x1fffu);
      const float4* e4 = (const float4*)(emb + ((size_t)code << 9));
      const float4 ea = e4[lane << 1], eb = e4[(lane << 1) + 1];
      double s = 0.0, d;
      d = (double)pa.x - ea.x; s += d * d;  d = (double)pa.y - ea.y; s += d * d;
      d = (double)pa.z - ea.z; s += d * d;  d = (double)pa.w - ea.w; s += d * d;
      d = (double)pb.x - eb.x; s += d * d;  d = (double)pb.y - eb.y; s += d * d;
      d = (double)pb.z - eb.z; s += d * d;  d = (double)pb.w - eb.w; s += d * d;
      #pragma unroll
      for(int off = 32; off; off >>= 1) s += __shfl_xor(s, off);
      if(s < bestd || (s == bestd && code < besti)){ bestd = s; besti = code; }
    }
  }
  __shared__ double se[4];
  if(lane == 0){ idxf[row] = besti; se[wv] = bestd; }
  __syncthreads();
  if(threadIdx.x == 0) part[blockIdx.x] = se[0] + se[1] + se[2] + se[3];
}

__global__ void k_loss(const double* __restrict__ part, const int* __restrict__ cnt,
                       float* __restrict__ out_loss){
  const int tid = threadIdx.x;
  double s = 0.0;
  for(int i = tid; i < 4096; i += 256) s += part[i];
  #pragma unroll
  for(int off = 32; off; off >>= 1) s += __shfl_xor(s, off);
  __shared__ double sb[4];
  if((tid & 63) == 0) sb[tid >> 6] = s;
  __syncthreads();
  if(tid == 0){
    const double e  = sb[0] + sb[1] + sb[2] + sb[3];
    const double el = e / (double)((size_t)N_ * 512);
    const double bm = (double)(*cnt) / 131072.0 - 0.125;
    const double loss = 0.25 * el + 0.01 * bm * bm;
    *out_loss = (float)loss;
  }
}

// expand codes over SPAN: one wave per segment, 16 coalesced 1KB stores
__launch_bounds__(256)
__global__ void k_expand(const float4* __restrict__ emb4, const int* __restrict__ idxf,
                         float4* __restrict__ q4, float* __restrict__ idxo){
  const int lane = threadIdx.x & 63, wv = threadIdx.x >> 6;
  const int seg = (blockIdx.x << 2) + wv;      // 0..16383
  const int idx = idxf[seg];
  const float4 a = emb4[idx * 128 + (lane << 1)];
  const float4 b = emb4[idx * 128 + (lane << 1) + 1];
  float4* dst = q4 + ((size_t)seg << 10);
  #pragma unroll
  for(int t = 0; t < 8; t++){
    dst[t * 128 + (lane << 1)]     = a;
    dst[t * 128 + (lane << 1) + 1] = b;
  }
  if(lane < 8) idxo[(seg << 3) + lane] = (float)idx;
}

extern "C" void kernel_launch(void* const* d_in, const int* in_sizes, int n_in,
                              void* d_out, int out_size, void* d_ws, size_t ws_size,
                              hipStream_t stream){
  const float* x   = (const float*)d_in[0];
  const float* emb = (const float*)d_in[1];
  const float* wb  = (const float*)d_in[2];
  const float* bb  = (const float*)d_in[3];
  float* out = (float*)d_out;

  // small workspace fields
  char* ws = (char*)d_ws;
  int*    cnt   = (int*)(ws + 0);
  double* part  = (double*)(ws + 64);       // 4096 doubles
  float*  enorm = (float*)(ws + 32832);     // 8192 floats
  int*    idxf  = (int*)(ws + 65600);       // 16384 ints

  // big scratch inside the quantized_out region (overwritten last by k_expand)
  float*              pooled  = (float*)d_out;                                        // 32 MB @ 0
  unsigned long long* cand64  = (unsigned long long*)((char*)d_out + (48ull  << 20)); // 16 MB @ 48M
  unsigned short*     pooledh = (unsigned short*)((char*)d_out + (80ull  << 20));     // 16 MB @ 80M
  unsigned short*     embh    = (unsigned short*)((char*)d_out + (100ull << 20));     //  8 MB @ 100M

  float* bnd   = out + BND_OFF;
  float* idxo  = out + IDX_OFF;
  float* lossp = out + LOSS_OFF;

  hipLaunchKernelGGL(k_embnorm, dim3(2048),  dim3(256), 0, stream, (const float4*)emb, enorm, embh, cnt);
  hipLaunchKernelGGL(k_prep,    dim3(4096),  dim3(256), 0, stream, (const float4*)x, (const float4*)wb,
                     bb, (float4*)pooled, pooledh, bnd, cnt);
  hipLaunchKernelGGL(k_distx,   dim3(2048),  dim3(512), 0, stream, pooledh, embh, enorm, cand64);
  hipLaunchKernelGGL(k_fixup,   dim3(4096),  dim3(256), 0, stream, pooled, emb, cand64, idxf, part);
  hipLaunchKernelGGL(k_loss,    dim3(1),     dim3(256), 0, stream, part, cnt, lossp);
  hipLaunchKernelGGL(k_expand,  dim3(4096),  dim3(256), 0, stream, (const float4*)emb, idxf, (float4*)d_out, idxo);
}